// Round 14
// baseline (282.223 us; speedup 1.0000x reference)
//
#include <hip/hip_runtime.h>
#include <hip/hip_bf16.h>

#define B 512
#define N 102
#define Pdim 12
#define H 256
#define M 4
#define E 3
#define NEG (-1e9f)
#define RT 52224   // B*N
#define NN 10404   // N*N

typedef __hip_bfloat16 bf16;
typedef __attribute__((ext_vector_type(8))) short short8;
typedef __attribute__((ext_vector_type(4))) float f32x4;
typedef __attribute__((ext_vector_type(16))) float f32x16;

__device__ __forceinline__ float b2f(bf16 v) { return __bfloat162float(v); }
__device__ __forceinline__ bf16 f2b(float v) { return __float2bfloat16(v); }
__device__ __forceinline__ short f2bs(float v) {
    bf16 t = __float2bfloat16(v);
    return *reinterpret_cast<short*>(&t);
}
__device__ __forceinline__ float fast_tanh(float x) {
    float e = __expf(2.f * x);
    return 1.f - 2.f * __builtin_amdgcn_rcpf(e + 1.f);
}
// async global->LDS, 4B/lane: wave writes 256B at wave-uniform LDS base.
__device__ __forceinline__ void gload_lds4(const unsigned int* g, unsigned int* l) {
    __builtin_amdgcn_global_load_lds(
        (const __attribute__((address_space(1))) unsigned int*)g,
        (__attribute__((address_space(3))) unsigned int*)l, 4, 0, 0);
}

// ---------------- weight prep + adjacency pre-pass ----------------
__global__ __launch_bounds__(256) void wt_prep(const float* __restrict__ Wrel,
                                               const float* __restrict__ Wself,
                                               const float* __restrict__ Wref,
                                               const float* __restrict__ Wref2,
                                               const float* __restrict__ Wmh,
                                               const float* __restrict__ Wq2,
                                               const float* __restrict__ W_q,
                                               const float* __restrict__ Vec,
                                               const float* __restrict__ W_emb,
                                               const float* __restrict__ dec,
                                               const float* __restrict__ v1,
                                               const float* __restrict__ adj,
                                               short* __restrict__ wfrag,
                                               short* __restrict__ wrefT,
                                               short* __restrict__ wref2T,
                                               short* __restrict__ wmh_bf,
                                               short* __restrict__ wq2_bf,
                                               short* __restrict__ wq_bf,
                                               short* __restrict__ wembf,
                                               short* __restrict__ adjp,
                                               float* __restrict__ qconst,
                                               float* __restrict__ vsum) {
    int bid = blockIdx.x;
    int tid = threadIdx.x;
    __shared__ short tl[1024 * 17];
    if (bid >= 3652) {
        int be = bid - 3652;
        const float* src = adj + (size_t)be * NN;
        short* dst = adjp + (size_t)be * (112 * 128);
        for (int i = tid; i < 112 * 128; i += 256) {
            int n = i >> 7, m = i & 127;
            short v = 0;
            if (n < N && m < N) v = f2bs(src[n * N + m]);
            dst[i] = v;
        }
        return;
    }
    if (bid < 32) {
        int hop = bid >> 4, ct = bid & 15;
        for (int i = tid; i < 16384; i += 256) {
            int k = i >> 4, c0 = i & 15;
            int c = ct * 16 + c0;
            float v;
            if (k < 768) v = Wrel[(((size_t)hop * E + (k >> 8)) * H + (k & 255)) * H + c];
            else         v = Wself[((size_t)hop * H + (k - 768)) * H + c];
            tl[k * 17 + c0] = f2bs(v);
        }
        __syncthreads();
        short8* outp = (short8*)wfrag + (size_t)(hop * 16 + ct) * 2048;
        for (int i = tid; i < 2048; i += 256) {
            int ks = i >> 6, lq = i & 63;
            int c0 = lq & 15, kb = (lq >> 4) * 8;
            short8 v;
#pragma unroll
            for (int j = 0; j < 8; ++j) v[j] = tl[(ks * 32 + kb + j) * 17 + c0];
            outp[i] = v;
        }
        return;
    }
    if (bid >= 3648) {
        int m = bid - 3648, hh = tid;
        __shared__ float dls[H], vls[H];
        dls[hh] = dec[hh];
        vls[hh] = v1[hh];
        __syncthreads();
        const float* Wm = W_q + (size_t)m * (3 * H) * H;
        float s = 0.f;
        for (int f = 0; f < H; ++f)
            s += dls[f] * Wm[(H + f) * H + hh] + vls[f] * Wm[(2 * H + f) * H + hh];
        qconst[m * H + hh] = s;
        float vs = 0.f;
        const float* Vr = Vec + ((size_t)m * H + hh) * H;
        for (int k = 0; k < H; ++k) vs += Vr[k];
        vsum[m * H + hh] = vs;
        return;
    }
    int idx = 524288 + (bid - 32) * 256 + tid;
    if (idx < 786432) {
        int r = idx - 524288;            // (m*256+c)*256 + k
        int row = r >> 8, k = r & 255;
        int m = row >> 8, c = row & 255;
        wrefT[r] = f2bs(Wref[((size_t)m * H + k) * H + c]);
    } else if (idx < 851968) {
        int r = idx - 786432;
        int c = r >> 8, k = r & 255;
        wref2T[r] = f2bs(Wref2[k * H + c]);
    } else if (idx < 1114112) {
        int r = idx - 851968;
        wmh_bf[r] = f2bs(Wmh[r]);
    } else if (idx < 1179648) {
        int r = idx - 1114112;
        wq2_bf[r] = f2bs(Wq2[r]);
    } else if (idx < 1441792) {
        int r = idx - 1179648;          // m*65536 + f*256 + hh
        int m = r >> 16, fh = r & 65535;
        wq_bf[r] = f2bs(W_q[(size_t)m * 768 * 256 + fh]);
    } else if (idx < 1449984) {
        int r = idx - 1441792;          // [ct:16][l:64][j:8]
        int ct = r >> 9, lq = (r >> 3) & 63, j = r & 7;
        int c = ct * 16 + (lq & 15), k = (lq >> 4) * 8 + j;
        wembf[r] = (k < Pdim) ? f2bs(W_emb[k * H + c]) : (short)0;
    }
}

// ------------- fused encoder: embed + 2 hops + mean, h resident in LDS -------------
#define HP 264     // hS pitch (shorts)
#define YP2 136    // Yt pitch (shorts)
#define ASP 136    // As pitch (shorts)
__global__ __launch_bounds__(512, 2) void enc_fused(const float* __restrict__ nf,
                                                    const short* __restrict__ wembf,
                                                    const short* __restrict__ adjp,
                                                    const short* __restrict__ wfragp,
                                                    bf16* __restrict__ enc_out,
                                                    float* __restrict__ mean_out) {
    int b = blockIdx.x;
    int tid = threadIdx.x;
    int w = tid >> 6;          // 0..7
    int l = tid & 63;
    int cg = l & 15;
    int rg = l >> 4;           // 0..3
    int ct0 = 2 * w, ct1 = ct0 + 1;

    __shared__ short hS[112 * HP];
    __shared__ short YtS[256 * YP2];
    __shared__ short AsS[112 * ASP];

    const short8 z8 = {0, 0, 0, 0, 0, 0, 0, 0};
    for (int i = tid; i < 10 * 32; i += 512) {
        int n = 102 + (i >> 5), g = i & 31;
        *(short8*)(&hS[n * HP + g * 8]) = z8;
    }
    {
        int c = tid >> 1, g = 14 + (tid & 1);
        *(short8*)(&YtS[c * YP2 + g * 8]) = z8;
    }

    // ---- embed via MFMA (K padded 12->32) ----
    {
        const short8* we8 = (const short8*)wembf;
        short8 bfe0 = we8[ct0 * 64 + l];
        short8 bfe1 = we8[ct1 * 64 + l];
#pragma unroll
        for (int nt = 0; nt < 7; ++nt) {
            int row = nt * 16 + cg;
            short8 afr = z8;
            if (row < 102 && rg < 2) {
                const float* src = nf + ((size_t)b * N + row) * Pdim + rg * 8;
                f32x4 v0 = *(const f32x4*)src;
                afr[0] = f2bs(v0[0]); afr[1] = f2bs(v0[1]);
                afr[2] = f2bs(v0[2]); afr[3] = f2bs(v0[3]);
                if (rg == 0) {
                    f32x4 v1 = *(const f32x4*)(src + 4);
                    afr[4] = f2bs(v1[0]); afr[5] = f2bs(v1[1]);
                    afr[6] = f2bs(v1[2]); afr[7] = f2bs(v1[3]);
                }
            }
            f32x4 d0 = (f32x4){0.f, 0.f, 0.f, 0.f}, d1 = d0;
            d0 = __builtin_amdgcn_mfma_f32_16x16x32_bf16(afr, bfe0, d0, 0, 0, 0);
            d1 = __builtin_amdgcn_mfma_f32_16x16x32_bf16(afr, bfe1, d1, 0, 0, 0);
#pragma unroll
            for (int r = 0; r < 4; ++r) {
                int n = nt * 16 + rg * 4 + r;
                hS[n * HP + ct0 * 16 + cg] = f2bs(d0[r]);
                hS[n * HP + ct1 * 16 + cg] = f2bs(d1[r]);
            }
        }
    }
    __syncthreads();

    for (int hop = 0; hop < 2; ++hop) {
        const short8* wf8 = ((const short8*)wfragp) + (size_t)hop * 32768;
        f32x4 hacc0[7], hacc1[7];
#pragma unroll
        for (int j = 0; j < 7; ++j) {
            hacc0[j] = (f32x4){0.f, 0.f, 0.f, 0.f};
            hacc1[j] = hacc0[j];
        }

        for (int estep = 0; estep < E; ++estep) {
            int e = hop ? (2 - estep) : estep;
            if (!(hop == 1 && estep == 0)) {
                const short* Abase = adjp + (size_t)(b * E + e) * 14336;
#pragma unroll
                for (int j = 0; j < 14; ++j) {
                    int n = w * 14 + j;
                    const unsigned int* gsrc = (const unsigned int*)(Abase + n * 128) + l;
                    gload_lds4(gsrc, (unsigned int*)&AsS[n * ASP]);
                }
            }
            if (estep == 0) {
#pragma unroll
                for (int ks = 0; ks < 8; ++ks) {
                    short8 wfs0 = wf8[(ct0 * 32 + 24 + ks) * 64 + l];
                    short8 wfs1 = wf8[(ct1 * 32 + 24 + ks) * 64 + l];
#pragma unroll
                    for (int nt = 0; nt < 7; ++nt) {
                        short8 hf = *(const short8*)(&hS[(nt * 16 + cg) * HP + ks * 32 + rg * 8]);
                        hacc0[nt] = __builtin_amdgcn_mfma_f32_16x16x32_bf16(hf, wfs0, hacc0[nt], 0, 0, 0);
                        hacc1[nt] = __builtin_amdgcn_mfma_f32_16x16x32_bf16(hf, wfs1, hacc1[nt], 0, 0, 0);
                    }
                }
            }
            // ---- Y phase ----
            f32x4 g0[7], g1[7];
#pragma unroll
            for (int j = 0; j < 7; ++j) {
                g0[j] = (f32x4){0.f, 0.f, 0.f, 0.f};
                g1[j] = g0[j];
            }
#pragma unroll
            for (int ks = 0; ks < 8; ++ks) {
                short8 wfa0 = wf8[(ct0 * 32 + e * 8 + ks) * 64 + l];
                short8 wfa1 = wf8[(ct1 * 32 + e * 8 + ks) * 64 + l];
#pragma unroll
                for (int mt = 0; mt < 7; ++mt) {
                    short8 hf = *(const short8*)(&hS[(mt * 16 + cg) * HP + ks * 32 + rg * 8]);
                    g0[mt] = __builtin_amdgcn_mfma_f32_16x16x32_bf16(wfa0, hf, g0[mt], 0, 0, 0);
                    g1[mt] = __builtin_amdgcn_mfma_f32_16x16x32_bf16(wfa1, hf, g1[mt], 0, 0, 0);
                }
            }
            // ---- Yt write ----
#pragma unroll
            for (int mt = 0; mt < 7; ++mt)
#pragma unroll
                for (int r = 0; r < 4; ++r) {
                    int c0 = ct0 * 16 + rg * 4 + r;
                    int c1 = ct1 * 16 + rg * 4 + r;
                    YtS[c0 * YP2 + mt * 16 + cg] = f2bs(g0[mt][r]);
                    YtS[c1 * YP2 + mt * 16 + cg] = f2bs(g1[mt][r]);
                }
            __syncthreads();
            // ---- gather ----
#pragma unroll
            for (int ks = 0; ks < 4; ++ks) {
                short8 yf0 = *(const short8*)(&YtS[(ct0 * 16 + cg) * YP2 + (ks * 4 + rg) * 8]);
                short8 yf1 = *(const short8*)(&YtS[(ct1 * 16 + cg) * YP2 + (ks * 4 + rg) * 8]);
#pragma unroll
                for (int nt = 0; nt < 7; ++nt) {
                    short8 af = *(const short8*)(&AsS[(nt * 16 + cg) * ASP + ks * 32 + rg * 8]);
                    hacc0[nt] = __builtin_amdgcn_mfma_f32_16x16x32_bf16(af, yf0, hacc0[nt], 0, 0, 0);
                    hacc1[nt] = __builtin_amdgcn_mfma_f32_16x16x32_bf16(af, yf1, hacc1[nt], 0, 0, 0);
                }
            }
            __syncthreads();
        }
        // ---- h update ----
#pragma unroll
        for (int nt = 0; nt < 7; ++nt)
#pragma unroll
            for (int r = 0; r < 4; ++r) {
                int n = nt * 16 + rg * 4 + r;
                float v0 = hacc0[nt][r], v1 = hacc1[nt][r];
                hS[n * HP + ct0 * 16 + cg] = f2bs(v0 > 0.f ? v0 : 0.f);
                hS[n * HP + ct1 * 16 + cg] = f2bs(v1 > 0.f ? v1 : 0.f);
            }
        __syncthreads();
    }

    // ---- write enc + mean ----
    short* ho = (short*)enc_out;
    for (int i = tid; i < 102 * 32; i += 512) {
        int n = i >> 5, g = i & 31;
        *(short8*)(ho + ((size_t)b * N + n) * H + g * 8) = *(const short8*)(&hS[n * HP + g * 8]);
    }
    {
        float* partf = (float*)AsS;
        int c = tid & 255, qq = tid >> 8;
        float s = 0.f;
        for (int n = qq; n < N; n += 2) s += b2f(*(const bf16*)&hS[n * HP + c]);
        partf[qq * 256 + c] = s;
        __syncthreads();
        if (tid < 256)
            mean_out[(size_t)b * H + tid] = (partf[tid] + partf[256 + tid]) * (1.f / (float)N);
    }
}

// ---------------- q[b,m,h] (bf16 W_q) ----------------
__global__ __launch_bounds__(256) void q_k(const float* __restrict__ enc_mean,
                                           const short* __restrict__ wq_bf,
                                           const float* __restrict__ qconst,
                                           float* __restrict__ qbuf) {
    int bid = blockIdx.x;
    int b = bid >> 2, m = bid & 3;
    int hh = threadIdx.x;
    __shared__ float em[H];
    em[hh] = enc_mean[(size_t)b * H + hh];
    __syncthreads();
    const bf16* Wm = (const bf16*)(wq_bf + (size_t)m * 65536);
    float s = qconst[m * H + hh];
    for (int f = 0; f < H; ++f) s += em[f] * b2f(Wm[f * H + hh]);
    qbuf[((size_t)b * M + m) * H + hh] = s;
}

// ------------- fused decoder: one block per b -------------
// Stages enc[b] swizzled once; glimpse MFMA (4 heads) -> masked softmax -> ctx
// (reads swizzled Xs in place) -> query2 chain -> final head MFMA -> log_softmax.
__global__ __launch_bounds__(256, 2) void dec_fused(const bf16* __restrict__ X,
                                                    const short* __restrict__ wrefT,
                                                    const short* __restrict__ wref2T,
                                                    const float* __restrict__ qb,
                                                    const float* __restrict__ vsb,
                                                    const short* __restrict__ wmh,
                                                    const short* __restrict__ wq2,
                                                    const float* __restrict__ Vec2,
                                                    const int* __restrict__ mask,
                                                    float* __restrict__ out) {
    int b = blockIdx.x;
    int tid = threadIdx.x;
    int w = tid >> 6, l = tid & 63;
    int lr = l & 31, lh = l >> 5;
    __shared__ short Xs[128 * 256];      // 64KB, swizzled; rows >=102 zero
    __shared__ float qls[M * 256];       // glimpse q
    __shared__ float part[4][128];
    __shared__ float a[M][128];          // scores -> softmax weights
    __shared__ float red[M];
    __shared__ float cx[M * 256];
    __shared__ float qy[256];
    __shared__ float q2s[256];
    __shared__ float fr[2];

    const short8 z8 = {0, 0, 0, 0, 0, 0, 0, 0};
    const short* Xp = (const short*)X;
#pragma unroll
    for (int i = 0; i < 16; ++i) {
        int id = tid + i * 256;
        int r = id >> 5, g = id & 31;
        short8 v = z8;
        if (r < N) v = *(const short8*)(Xp + ((size_t)b * N + r) * H + g * 8);
        *(short8*)((char*)Xs + r * 512 + ((g ^ (r & 7)) * 16)) = v;
    }
    for (int i = tid; i < M * 256; i += 256) qls[i] = qb[(size_t)b * (M * H) + i];
    __syncthreads();

    int swz = lr & 7;
    // ---- glimpse scores, head m ----
    for (int m = 0; m < M; ++m) {
        const short8* w8 = (const short8*)(wrefT + (size_t)m * H * H);
        int cbase = w * 64;
        short8 afr0[16], afr1[16];
#pragma unroll
        for (int ks = 0; ks < 16; ++ks) {
            afr0[ks] = w8[(size_t)(cbase + lr) * 32 + ks * 2 + lh];
            afr1[ks] = w8[(size_t)(cbase + 32 + lr) * 32 + ks * 2 + lh];
        }
        float vsl[32];
#pragma unroll
        for (int j = 0; j < 16; ++j) {
            int cl = (j & 3) + 8 * (j >> 2) + 4 * lh;
            vsl[j]      = vsb[m * H + w * 64 + cl];
            vsl[16 + j] = vsb[m * H + w * 64 + 32 + cl];
        }
        const float* qrow = &qls[m * 256];
        for (int t = 0; t < 4; ++t) {
            f32x16 acc0, acc1;
#pragma unroll
            for (int j = 0; j < 16; ++j) { acc0[j] = 0.f; acc1[j] = 0.f; }
            const char* xbase = (const char*)Xs + (t * 32 + lr) * 512;
#pragma unroll
            for (int ks = 0; ks < 16; ++ks) {
                short8 bx = *(const short8*)(xbase + (((2 * ks + lh) ^ swz) * 16));
                acc0 = __builtin_amdgcn_mfma_f32_32x32x16_bf16(afr0[ks], bx, acc0, 0, 0, 0);
                acc1 = __builtin_amdgcn_mfma_f32_32x32x16_bf16(afr1[ks], bx, acc1, 0, 0, 0);
            }
            float s = 0.f;
#pragma unroll
            for (int j = 0; j < 16; ++j) {
                int cl = (j & 3) + 8 * (j >> 2) + 4 * lh;
                s += fast_tanh(qrow[w * 64 + cl] + acc0[j]) * vsl[j];
                s += fast_tanh(qrow[w * 64 + 32 + cl] + acc1[j]) * vsl[16 + j];
            }
            s += __shfl_xor(s, 32, 64);
            if (l < 32) part[w][t * 32 + lr] = s;
        }
        __syncthreads();
        if (tid < 128) {
            int n = tid;
            float s = part[0][n] + part[1][n] + part[2][n] + part[3][n];
            if (n >= N || mask[(size_t)b * N + (n < N ? n : 0)] > 0) s = NEG;
            a[m][n] = s;
        }
        __syncthreads();
    }

    // ---- softmax per head (wave w = head w) ----
    {
        float v = fmaxf(a[w][l], a[w][l + 64]);
        v = fmaxf(v, __shfl_xor(v, 32, 64));
        v = fmaxf(v, __shfl_xor(v, 16, 64));
        v = fmaxf(v, __shfl_xor(v, 8, 64));
        v = fmaxf(v, __shfl_xor(v, 4, 64));
        v = fmaxf(v, __shfl_xor(v, 2, 64));
        v = fmaxf(v, __shfl_xor(v, 1, 64));
        float mx = __shfl(v, 0, 64);
        float e0 = __expf(a[w][l] - mx);
        float e1 = __expf(a[w][l + 64] - mx);
        a[w][l] = e0;
        a[w][l + 64] = e1;
        float sv = e0 + e1;
        sv += __shfl_xor(sv, 32, 64);
        sv += __shfl_xor(sv, 16, 64);
        sv += __shfl_xor(sv, 8, 64);
        sv += __shfl_xor(sv, 4, 64);
        sv += __shfl_xor(sv, 2, 64);
        sv += __shfl_xor(sv, 1, 64);
        if (l == 0) red[w] = __builtin_amdgcn_rcpf(sv);
    }
    __syncthreads();
    // ---- ctx: thread = channel; read enc from swizzled Xs in place ----
    {
        int g = tid >> 3, bo = (tid & 7) * 2;
        float c0 = 0.f, c1 = 0.f, c2 = 0.f, c3 = 0.f;
        for (int n = 0; n < N; ++n) {
            float e = b2f(*(const bf16*)((const char*)Xs + n * 512 + ((g ^ (n & 7)) << 4) + bo));
            c0 += a[0][n] * e;
            c1 += a[1][n] * e;
            c2 += a[2][n] * e;
            c3 += a[3][n] * e;
        }
        cx[0 * 256 + tid] = c0 * red[0];
        cx[1 * 256 + tid] = c1 * red[1];
        cx[2 * 256 + tid] = c2 * red[2];
        cx[3 * 256 + tid] = c3 * red[3];
    }
    __syncthreads();
    // ---- query2 chain ----
    {
        const bf16* wm = (const bf16*)wmh;
        float acc = 0.f;
        for (int j = 0; j < M * H; ++j) acc += cx[j] * b2f(wm[(size_t)j * H + tid]);
        qy[tid] = acc;
    }
    __syncthreads();
    {
        const bf16* w2 = (const bf16*)wq2;
        float acc2 = 0.f;
        for (int k = 0; k < H; ++k) acc2 += qy[k] * b2f(w2[(size_t)k * H + tid]);
        q2s[tid] = acc2;
    }
    __syncthreads();

    // ---- final pointer head ----
    {
        const short8* w8 = (const short8*)wref2T;
        int cbase = w * 64;
        short8 afr0[16], afr1[16];
#pragma unroll
        for (int ks = 0; ks < 16; ++ks) {
            afr0[ks] = w8[(size_t)(cbase + lr) * 32 + ks * 2 + lh];
            afr1[ks] = w8[(size_t)(cbase + 32 + lr) * 32 + ks * 2 + lh];
        }
        float vsl[32];
#pragma unroll
        for (int j = 0; j < 16; ++j) {
            int cl = (j & 3) + 8 * (j >> 2) + 4 * lh;
            vsl[j]      = Vec2[w * 64 + cl];
            vsl[16 + j] = Vec2[w * 64 + 32 + cl];
        }
        for (int t = 0; t < 4; ++t) {
            f32x16 acc0, acc1;
#pragma unroll
            for (int j = 0; j < 16; ++j) { acc0[j] = 0.f; acc1[j] = 0.f; }
            const char* xbase = (const char*)Xs + (t * 32 + lr) * 512;
#pragma unroll
            for (int ks = 0; ks < 16; ++ks) {
                short8 bx = *(const short8*)(xbase + (((2 * ks + lh) ^ swz) * 16));
                acc0 = __builtin_amdgcn_mfma_f32_32x32x16_bf16(afr0[ks], bx, acc0, 0, 0, 0);
                acc1 = __builtin_amdgcn_mfma_f32_32x32x16_bf16(afr1[ks], bx, acc1, 0, 0, 0);
            }
            float s = 0.f;
#pragma unroll
            for (int j = 0; j < 16; ++j) {
                int cl = (j & 3) + 8 * (j >> 2) + 4 * lh;
                s += fast_tanh(q2s[w * 64 + cl] + acc0[j]) * vsl[j];
                s += fast_tanh(q2s[w * 64 + 32 + cl] + acc1[j]) * vsl[16 + j];
            }
            s += __shfl_xor(s, 32, 64);
            if (l < 32) part[w][t * 32 + lr] = s;
        }
        __syncthreads();
        if (tid < 128) {
            int n = tid;
            float u = NEG;
            if (n < N && mask[(size_t)b * N + n] <= 0) {
                float u2 = part[0][n] + part[1][n] + part[2][n] + part[3][n];
                u = 10.f * fast_tanh(u2);
            }
            a[0][n] = u;
        }
    }
    __syncthreads();
    // ---- log_softmax over n ----
    if (tid < 64) {
        float v = fmaxf(a[0][tid], a[0][tid + 64]);
        v = fmaxf(v, __shfl_xor(v, 32, 64));
        v = fmaxf(v, __shfl_xor(v, 16, 64));
        v = fmaxf(v, __shfl_xor(v, 8, 64));
        v = fmaxf(v, __shfl_xor(v, 4, 64));
        v = fmaxf(v, __shfl_xor(v, 2, 64));
        v = fmaxf(v, __shfl_xor(v, 1, 64));
        if (tid == 0) fr[0] = v;
    }
    __syncthreads();
    float mx = fr[0];
    if (tid < 128) part[0][tid] = __expf(a[0][tid] - mx);
    __syncthreads();
    if (tid < 64) {
        float v = part[0][tid] + part[0][tid + 64];
        v += __shfl_xor(v, 32, 64);
        v += __shfl_xor(v, 16, 64);
        v += __shfl_xor(v, 8, 64);
        v += __shfl_xor(v, 4, 64);
        v += __shfl_xor(v, 2, 64);
        v += __shfl_xor(v, 1, 64);
        if (tid == 0) fr[1] = logf(v);
    }
    __syncthreads();
    if (tid < N) out[(size_t)b * N + tid] = (a[0][tid] - mx) - fr[1];
}

extern "C" void kernel_launch(void* const* d_in, const int* in_sizes, int n_in,
                              void* d_out, int out_size, void* d_ws, size_t ws_size,
                              hipStream_t stream) {
    const float* nf     = (const float*)d_in[0];
    const float* adj    = (const float*)d_in[1];
    const int*   mask   = (const int*)d_in[2];
    const float* W_emb  = (const float*)d_in[3];
    const float* W_rel  = (const float*)d_in[4];
    const float* W_self = (const float*)d_in[5];
    const float* Vec    = (const float*)d_in[6];
    const float* W_q    = (const float*)d_in[7];
    const float* W_ref  = (const float*)d_in[8];
    const float* W_mh   = (const float*)d_in[9];
    const float* Vec2   = (const float*)d_in[10];
    const float* W_q2   = (const float*)d_in[11];
    const float* W_ref2 = (const float*)d_in[12];
    const float* dec    = (const float*)d_in[13];
    const float* v_1    = (const float*)d_in[14];
    float* out = (float*)d_out;

    char* p = (char*)d_ws;
    size_t off = 0;
    auto alloc = [&](size_t bytes) -> char* {
        char* q = p + off;
        off += (bytes + 255) & ~(size_t)255;
        return q;
    };
    bf16* hA      = (bf16*)alloc((size_t)RT * H * sizeof(bf16));
    short* adjp   = (short*)alloc((size_t)B * E * 112 * 128 * sizeof(short));
    short* wfrag  = (short*)alloc(524288 * sizeof(short));
    short* wrefT  = (short*)alloc(262144 * sizeof(short));
    short* wref2T = (short*)alloc(65536 * sizeof(short));
    short* wmh_bf = (short*)alloc(262144 * sizeof(short));
    short* wq2_bf = (short*)alloc(65536 * sizeof(short));
    short* wq_bf  = (short*)alloc(262144 * sizeof(short));
    short* wembf  = (short*)alloc(8192 * sizeof(short));
    float* enc_mean = (float*)alloc((size_t)B * H * sizeof(float));
    float* qconst   = (float*)alloc((size_t)M * H * sizeof(float));
    float* vsumb    = (float*)alloc((size_t)M * H * sizeof(float));
    float* qbuf     = (float*)alloc((size_t)B * M * H * sizeof(float));

    wt_prep<<<5188, 256, 0, stream>>>(W_rel, W_self, W_ref, W_ref2, W_mh, W_q2,
                                      W_q, Vec, W_emb, dec, v_1, adj,
                                      wfrag, wrefT, wref2T, wmh_bf, wq2_bf, wq_bf, wembf,
                                      adjp, qconst, vsumb);

    enc_fused<<<B, 512, 0, stream>>>(nf, wembf, adjp, wfrag, hA, enc_mean);

    const bf16* enc = hA;

    q_k<<<B * M, 256, 0, stream>>>(enc_mean, wq_bf, qconst, qbuf);
    dec_fused<<<B, 256, 0, stream>>>(enc, wrefT, wref2T, qbuf, vsumb,
                                     wmh_bf, wq2_bf, Vec2, mask, out);
}

// Round 15
// 266.132 us; speedup vs baseline: 1.0605x; 1.0605x over previous
//
#include <hip/hip_runtime.h>
#include <hip/hip_bf16.h>

#define B 512
#define N 102
#define Pdim 12
#define H 256
#define M 4
#define E 3
#define NEG (-1e9f)
#define RT 52224   // B*N
#define NN 10404   // N*N

typedef __hip_bfloat16 bf16;
typedef __attribute__((ext_vector_type(8))) short short8;
typedef __attribute__((ext_vector_type(4))) float f32x4;
typedef __attribute__((ext_vector_type(16))) float f32x16;

__device__ __forceinline__ float b2f(bf16 v) { return __bfloat162float(v); }
__device__ __forceinline__ bf16 f2b(float v) { return __float2bfloat16(v); }
__device__ __forceinline__ short f2bs(float v) {
    bf16 t = __float2bfloat16(v);
    return *reinterpret_cast<short*>(&t);
}
__device__ __forceinline__ float fast_tanh(float x) {
    float e = __expf(2.f * x);
    return 1.f - 2.f * __builtin_amdgcn_rcpf(e + 1.f);
}
// async global->LDS, 4B/lane: wave writes 256B at wave-uniform LDS base.
__device__ __forceinline__ void gload_lds4(const unsigned int* g, unsigned int* l) {
    __builtin_amdgcn_global_load_lds(
        (const __attribute__((address_space(1))) unsigned int*)g,
        (__attribute__((address_space(3))) unsigned int*)l, 4, 0, 0);
}

// ---------------- weight prep + adjacency pre-pass ----------------
__global__ __launch_bounds__(256) void wt_prep(const float* __restrict__ Wrel,
                                               const float* __restrict__ Wself,
                                               const float* __restrict__ Wref,
                                               const float* __restrict__ Wref2,
                                               const float* __restrict__ Wmh,
                                               const float* __restrict__ Wq2,
                                               const float* __restrict__ W_q,
                                               const float* __restrict__ Vec,
                                               const float* __restrict__ W_emb,
                                               const float* __restrict__ dec,
                                               const float* __restrict__ v1,
                                               const float* __restrict__ adj,
                                               short* __restrict__ wfrag,
                                               short* __restrict__ wrefT,
                                               short* __restrict__ wref2T,
                                               short* __restrict__ wmh_bf,
                                               short* __restrict__ wq2_bf,
                                               short* __restrict__ wq_bf,
                                               short* __restrict__ wembf,
                                               short* __restrict__ adjp,
                                               float* __restrict__ qconst,
                                               float* __restrict__ vsum) {
    int bid = blockIdx.x;
    int tid = threadIdx.x;
    __shared__ short tl[1024 * 17];
    if (bid >= 3652) {
        int be = bid - 3652;
        const float* src = adj + (size_t)be * NN;
        short* dst = adjp + (size_t)be * (112 * 128);
        for (int i = tid; i < 112 * 128; i += 256) {
            int n = i >> 7, m = i & 127;
            short v = 0;
            if (n < N && m < N) v = f2bs(src[n * N + m]);
            dst[i] = v;
        }
        return;
    }
    if (bid < 32) {
        int hop = bid >> 4, ct = bid & 15;
        for (int i = tid; i < 16384; i += 256) {
            int k = i >> 4, c0 = i & 15;
            int c = ct * 16 + c0;
            float v;
            if (k < 768) v = Wrel[(((size_t)hop * E + (k >> 8)) * H + (k & 255)) * H + c];
            else         v = Wself[((size_t)hop * H + (k - 768)) * H + c];
            tl[k * 17 + c0] = f2bs(v);
        }
        __syncthreads();
        short8* outp = (short8*)wfrag + (size_t)(hop * 16 + ct) * 2048;
        for (int i = tid; i < 2048; i += 256) {
            int ks = i >> 6, lq = i & 63;
            int c0 = lq & 15, kb = (lq >> 4) * 8;
            short8 v;
#pragma unroll
            for (int j = 0; j < 8; ++j) v[j] = tl[(ks * 32 + kb + j) * 17 + c0];
            outp[i] = v;
        }
        return;
    }
    if (bid >= 3648) {
        int m = bid - 3648, hh = tid;
        __shared__ float dls[H], vls[H];
        dls[hh] = dec[hh];
        vls[hh] = v1[hh];
        __syncthreads();
        const float* Wm = W_q + (size_t)m * (3 * H) * H;
        float s = 0.f;
        for (int f = 0; f < H; ++f)
            s += dls[f] * Wm[(H + f) * H + hh] + vls[f] * Wm[(2 * H + f) * H + hh];
        qconst[m * H + hh] = s;
        float vs = 0.f;
        const float* Vr = Vec + ((size_t)m * H + hh) * H;
        for (int k = 0; k < H; ++k) vs += Vr[k];
        vsum[m * H + hh] = vs;
        return;
    }
    int idx = 524288 + (bid - 32) * 256 + tid;
    if (idx < 786432) {
        int r = idx - 524288;            // (m*256+c)*256 + k
        int row = r >> 8, k = r & 255;
        int m = row >> 8, c = row & 255;
        wrefT[r] = f2bs(Wref[((size_t)m * H + k) * H + c]);
    } else if (idx < 851968) {
        int r = idx - 786432;
        int c = r >> 8, k = r & 255;
        wref2T[r] = f2bs(Wref2[k * H + c]);
    } else if (idx < 1114112) {
        int r = idx - 851968;
        wmh_bf[r] = f2bs(Wmh[r]);
    } else if (idx < 1179648) {
        int r = idx - 1114112;
        wq2_bf[r] = f2bs(Wq2[r]);
    } else if (idx < 1441792) {
        int r = idx - 1179648;          // m*65536 + f*256 + hh
        int m = r >> 16, fh = r & 65535;
        wq_bf[r] = f2bs(W_q[(size_t)m * 768 * 256 + fh]);
    } else if (idx < 1449984) {
        int r = idx - 1441792;          // [ct:16][l:64][j:8]
        int ct = r >> 9, lq = (r >> 3) & 63, j = r & 7;
        int c = ct * 16 + (lq & 15), k = (lq >> 4) * 8 + j;
        wembf[r] = (k < Pdim) ? f2bs(W_emb[k * H + c]) : (short)0;
    }
}

// ------------- fused encoder: embed + 2 hops + mean, h resident in LDS -------------
#define HP 264     // hS pitch (shorts)
#define YP2 136    // Yt pitch (shorts)
#define ASP 136    // As pitch (shorts)
__global__ __launch_bounds__(512, 2) void enc_fused(const float* __restrict__ nf,
                                                    const short* __restrict__ wembf,
                                                    const short* __restrict__ adjp,
                                                    const short* __restrict__ wfragp,
                                                    bf16* __restrict__ enc_out,
                                                    float* __restrict__ mean_out) {
    int b = blockIdx.x;
    int tid = threadIdx.x;
    int w = tid >> 6;          // 0..7
    int l = tid & 63;
    int cg = l & 15;
    int rg = l >> 4;           // 0..3
    int ct0 = 2 * w, ct1 = ct0 + 1;

    __shared__ short hS[112 * HP];
    __shared__ short YtS[256 * YP2];
    __shared__ short AsS[112 * ASP];

    const short8 z8 = {0, 0, 0, 0, 0, 0, 0, 0};
    for (int i = tid; i < 10 * 32; i += 512) {
        int n = 102 + (i >> 5), g = i & 31;
        *(short8*)(&hS[n * HP + g * 8]) = z8;
    }
    {
        int c = tid >> 1, g = 14 + (tid & 1);
        *(short8*)(&YtS[c * YP2 + g * 8]) = z8;
    }

    // ---- embed via MFMA (K padded 12->32) ----
    {
        const short8* we8 = (const short8*)wembf;
        short8 bfe0 = we8[ct0 * 64 + l];
        short8 bfe1 = we8[ct1 * 64 + l];
#pragma unroll
        for (int nt = 0; nt < 7; ++nt) {
            int row = nt * 16 + cg;
            short8 afr = z8;
            if (row < 102 && rg < 2) {
                const float* src = nf + ((size_t)b * N + row) * Pdim + rg * 8;
                f32x4 v0 = *(const f32x4*)src;
                afr[0] = f2bs(v0[0]); afr[1] = f2bs(v0[1]);
                afr[2] = f2bs(v0[2]); afr[3] = f2bs(v0[3]);
                if (rg == 0) {
                    f32x4 v1 = *(const f32x4*)(src + 4);
                    afr[4] = f2bs(v1[0]); afr[5] = f2bs(v1[1]);
                    afr[6] = f2bs(v1[2]); afr[7] = f2bs(v1[3]);
                }
            }
            f32x4 d0 = (f32x4){0.f, 0.f, 0.f, 0.f}, d1 = d0;
            d0 = __builtin_amdgcn_mfma_f32_16x16x32_bf16(afr, bfe0, d0, 0, 0, 0);
            d1 = __builtin_amdgcn_mfma_f32_16x16x32_bf16(afr, bfe1, d1, 0, 0, 0);
#pragma unroll
            for (int r = 0; r < 4; ++r) {
                int n = nt * 16 + rg * 4 + r;
                hS[n * HP + ct0 * 16 + cg] = f2bs(d0[r]);
                hS[n * HP + ct1 * 16 + cg] = f2bs(d1[r]);
            }
        }
    }
    __syncthreads();

    for (int hop = 0; hop < 2; ++hop) {
        const short8* wf8 = ((const short8*)wfragp) + (size_t)hop * 32768;
        f32x4 hacc0[7], hacc1[7];
#pragma unroll
        for (int j = 0; j < 7; ++j) {
            hacc0[j] = (f32x4){0.f, 0.f, 0.f, 0.f};
            hacc1[j] = hacc0[j];
        }

        for (int estep = 0; estep < E; ++estep) {
            int e = hop ? (2 - estep) : estep;
            if (!(hop == 1 && estep == 0)) {
                const short* Abase = adjp + (size_t)(b * E + e) * 14336;
#pragma unroll
                for (int j = 0; j < 14; ++j) {
                    int n = w * 14 + j;
                    const unsigned int* gsrc = (const unsigned int*)(Abase + n * 128) + l;
                    gload_lds4(gsrc, (unsigned int*)&AsS[n * ASP]);
                }
            }
            if (estep == 0) {
#pragma unroll
                for (int ks = 0; ks < 8; ++ks) {
                    short8 wfs0 = wf8[(ct0 * 32 + 24 + ks) * 64 + l];
                    short8 wfs1 = wf8[(ct1 * 32 + 24 + ks) * 64 + l];
#pragma unroll
                    for (int nt = 0; nt < 7; ++nt) {
                        short8 hf = *(const short8*)(&hS[(nt * 16 + cg) * HP + ks * 32 + rg * 8]);
                        hacc0[nt] = __builtin_amdgcn_mfma_f32_16x16x32_bf16(hf, wfs0, hacc0[nt], 0, 0, 0);
                        hacc1[nt] = __builtin_amdgcn_mfma_f32_16x16x32_bf16(hf, wfs1, hacc1[nt], 0, 0, 0);
                    }
                }
            }
            // ---- Y phase ----
            f32x4 g0[7], g1[7];
#pragma unroll
            for (int j = 0; j < 7; ++j) {
                g0[j] = (f32x4){0.f, 0.f, 0.f, 0.f};
                g1[j] = g0[j];
            }
#pragma unroll
            for (int ks = 0; ks < 8; ++ks) {
                short8 wfa0 = wf8[(ct0 * 32 + e * 8 + ks) * 64 + l];
                short8 wfa1 = wf8[(ct1 * 32 + e * 8 + ks) * 64 + l];
#pragma unroll
                for (int mt = 0; mt < 7; ++mt) {
                    short8 hf = *(const short8*)(&hS[(mt * 16 + cg) * HP + ks * 32 + rg * 8]);
                    g0[mt] = __builtin_amdgcn_mfma_f32_16x16x32_bf16(wfa0, hf, g0[mt], 0, 0, 0);
                    g1[mt] = __builtin_amdgcn_mfma_f32_16x16x32_bf16(wfa1, hf, g1[mt], 0, 0, 0);
                }
            }
            // ---- Yt write ----
#pragma unroll
            for (int mt = 0; mt < 7; ++mt)
#pragma unroll
                for (int r = 0; r < 4; ++r) {
                    int c0 = ct0 * 16 + rg * 4 + r;
                    int c1 = ct1 * 16 + rg * 4 + r;
                    YtS[c0 * YP2 + mt * 16 + cg] = f2bs(g0[mt][r]);
                    YtS[c1 * YP2 + mt * 16 + cg] = f2bs(g1[mt][r]);
                }
            __syncthreads();
            // ---- gather ----
#pragma unroll
            for (int ks = 0; ks < 4; ++ks) {
                short8 yf0 = *(const short8*)(&YtS[(ct0 * 16 + cg) * YP2 + (ks * 4 + rg) * 8]);
                short8 yf1 = *(const short8*)(&YtS[(ct1 * 16 + cg) * YP2 + (ks * 4 + rg) * 8]);
#pragma unroll
                for (int nt = 0; nt < 7; ++nt) {
                    short8 af = *(const short8*)(&AsS[(nt * 16 + cg) * ASP + ks * 32 + rg * 8]);
                    hacc0[nt] = __builtin_amdgcn_mfma_f32_16x16x32_bf16(af, yf0, hacc0[nt], 0, 0, 0);
                    hacc1[nt] = __builtin_amdgcn_mfma_f32_16x16x32_bf16(af, yf1, hacc1[nt], 0, 0, 0);
                }
            }
            __syncthreads();
        }
        // ---- h update ----
#pragma unroll
        for (int nt = 0; nt < 7; ++nt)
#pragma unroll
            for (int r = 0; r < 4; ++r) {
                int n = nt * 16 + rg * 4 + r;
                float v0 = hacc0[nt][r], v1 = hacc1[nt][r];
                hS[n * HP + ct0 * 16 + cg] = f2bs(v0 > 0.f ? v0 : 0.f);
                hS[n * HP + ct1 * 16 + cg] = f2bs(v1 > 0.f ? v1 : 0.f);
            }
        __syncthreads();
    }

    // ---- write enc + mean ----
    short* ho = (short*)enc_out;
    for (int i = tid; i < 102 * 32; i += 512) {
        int n = i >> 5, g = i & 31;
        *(short8*)(ho + ((size_t)b * N + n) * H + g * 8) = *(const short8*)(&hS[n * HP + g * 8]);
    }
    {
        float* partf = (float*)AsS;
        int c = tid & 255, qq = tid >> 8;
        float s = 0.f;
        for (int n = qq; n < N; n += 2) s += b2f(*(const bf16*)&hS[n * HP + c]);
        partf[qq * 256 + c] = s;
        __syncthreads();
        if (tid < 256)
            mean_out[(size_t)b * H + tid] = (partf[tid] + partf[256 + tid]) * (1.f / (float)N);
    }
}

// ------- head2: swapped-operand 32x32x16; X staged ONCE, loop over heads m -------
__global__ __launch_bounds__(256, 2) void head2_mfma(const bf16* __restrict__ X,
                                                     const short* __restrict__ WT,
                                                     const float* __restrict__ qb, int qbs,
                                                     const float* __restrict__ vsb,
                                                     float* __restrict__ outp, int obs,
                                                     int mcnt) {
    int rt = blockIdx.x;
    int r0 = rt * 128;
    int tid = threadIdx.x;
    int w = tid >> 6, l = tid & 63;
    int lr = l & 31;
    int lh = l >> 5;
    __shared__ short Xs[128 * 256];
    __shared__ float qls[12 * 256];
    __shared__ float part[4][128];

    const short* Xp = (const short*)X;
#pragma unroll
    for (int i = 0; i < 16; ++i) {
        int id = tid + i * 256;
        int r = id >> 5, g = id & 31;
        short8 v = *(const short8*)(Xp + (size_t)(r0 + r) * H + g * 8);
        *(short8*)((char*)Xs + r * 512 + ((g ^ (r & 7)) * 16)) = v;
    }
    int b_base = r0 / N;
    for (int i = tid; i < 3 * mcnt * 256; i += 256) {
        int boff = i / (mcnt * 256);
        int rem = i - boff * (mcnt * 256);
        int m = rem >> 8, c = rem & 255;
        int bb = b_base + boff;
        if (bb > B - 1) bb = B - 1;
        qls[(boff * mcnt + m) * 256 + c] = qb[(size_t)bb * qbs + m * H + c];
    }
    __syncthreads();

    int swz = lr & 7;
    for (int m = 0; m < mcnt; ++m) {
        const short8* w8 = (const short8*)(WT + (size_t)m * H * H);
        int cbase = w * 64;
        short8 afr0[16], afr1[16];
#pragma unroll
        for (int ks = 0; ks < 16; ++ks) {
            afr0[ks] = w8[(size_t)(cbase + lr) * 32 + ks * 2 + lh];
            afr1[ks] = w8[(size_t)(cbase + 32 + lr) * 32 + ks * 2 + lh];
        }
        float vsl[32];
#pragma unroll
        for (int j = 0; j < 16; ++j) {
            int cl = (j & 3) + 8 * (j >> 2) + 4 * lh;
            vsl[j]      = vsb[m * H + w * 64 + cl];
            vsl[16 + j] = vsb[m * H + w * 64 + 32 + cl];
        }
        for (int t = 0; t < 4; ++t) {
            f32x16 acc0, acc1;
#pragma unroll
            for (int j = 0; j < 16; ++j) { acc0[j] = 0.f; acc1[j] = 0.f; }
            const char* xbase = (const char*)Xs + (t * 32 + lr) * 512;
#pragma unroll
            for (int ks = 0; ks < 16; ++ks) {
                short8 bx = *(const short8*)(xbase + (((2 * ks + lh) ^ swz) * 16));
                acc0 = __builtin_amdgcn_mfma_f32_32x32x16_bf16(afr0[ks], bx, acc0, 0, 0, 0);
                acc1 = __builtin_amdgcn_mfma_f32_32x32x16_bf16(afr1[ks], bx, acc1, 0, 0, 0);
            }
            int r = r0 + t * 32 + lr;
            int b = r / N;
            int boff = b - b_base;
            const float* qrow = &qls[(boff * mcnt + m) * 256];
            float s = 0.f;
#pragma unroll
            for (int j = 0; j < 16; ++j) {
                int cl = (j & 3) + 8 * (j >> 2) + 4 * lh;
                float x0 = qrow[w * 64 + cl] + acc0[j];
                s += fast_tanh(x0) * vsl[j];
                float x1 = qrow[w * 64 + 32 + cl] + acc1[j];
                s += fast_tanh(x1) * vsl[16 + j];
            }
            s += __shfl_xor(s, 32, 64);
            if (l < 32) part[w][t * 32 + lr] = s;
        }
        __syncthreads();
        if (tid < 128) {
            int r = r0 + tid;
            int b = r / N, n = r - b * N;
            outp[(size_t)b * obs + m * N + n] = part[0][tid] + part[1][tid] + part[2][tid] + part[3][tid];
        }
        __syncthreads();
    }
}

// ---------------- q[b,m,h] (bf16 W_q) ----------------
__global__ __launch_bounds__(256) void q_k(const float* __restrict__ enc_mean,
                                           const short* __restrict__ wq_bf,
                                           const float* __restrict__ qconst,
                                           float* __restrict__ qbuf) {
    int bid = blockIdx.x;
    int b = bid >> 2, m = bid & 3;
    int hh = threadIdx.x;
    __shared__ float em[H];
    em[hh] = enc_mean[(size_t)b * H + hh];
    __syncthreads();
    const bf16* Wm = (const bf16*)(wq_bf + (size_t)m * 65536);
    float s = qconst[m * H + hh];
    for (int f = 0; f < H; ++f) s += em[f] * b2f(Wm[f * H + hh]);
    qbuf[((size_t)b * M + m) * H + hh] = s;
}

// ------- dec_mid: masked softmax + ctx + query2 fused, one block per b -------
__global__ __launch_bounds__(256) void dec_mid_k(const float* __restrict__ scores,
                                                 const int* __restrict__ mask,
                                                 const bf16* __restrict__ enc,
                                                 const short* __restrict__ wmh,
                                                 const short* __restrict__ wq2,
                                                 float* __restrict__ q2) {
    int b = blockIdx.x;
    int tid = threadIdx.x;
    int w = tid >> 6;
    int l = tid & 63;
    __shared__ short hEnc[102 * 264];
    __shared__ float a[M][112];
    __shared__ float red[M];
    __shared__ float cx[M * H];
    __shared__ float qy[H];

    const short* ep = (const short*)enc;
    for (int i = tid; i < 102 * 32; i += 256) {
        int n = i >> 5, g = i & 31;
        *(short8*)(&hEnc[n * 264 + g * 8]) = *(const short8*)(ep + ((size_t)b * N + n) * H + g * 8);
    }
    for (int i = tid; i < M * 112; i += 256) {
        int m = i / 112, n = i % 112;
        float s = NEG;
        if (n < N) s = (mask[(size_t)b * N + n] > 0) ? NEG : scores[((size_t)b * M + m) * N + n];
        a[m][n] = s;
    }
    __syncthreads();
    {
        float v = a[w][l];
        float v2 = (l + 64 < 112) ? a[w][l + 64] : NEG;
        v = fmaxf(v, v2);
        v = fmaxf(v, __shfl_xor(v, 32, 64));
        v = fmaxf(v, __shfl_xor(v, 16, 64));
        v = fmaxf(v, __shfl_xor(v, 8, 64));
        v = fmaxf(v, __shfl_xor(v, 4, 64));
        v = fmaxf(v, __shfl_xor(v, 2, 64));
        v = fmaxf(v, __shfl_xor(v, 1, 64));
        float mx = __shfl(v, 0, 64);
        float e0 = __expf(a[w][l] - mx);
        float e1 = (l + 64 < 112) ? __expf(a[w][l + 64] - mx) : 0.f;
        a[w][l] = e0;
        if (l + 64 < 112) a[w][l + 64] = e1;
        float sv = e0 + e1;
        sv += __shfl_xor(sv, 32, 64);
        sv += __shfl_xor(sv, 16, 64);
        sv += __shfl_xor(sv, 8, 64);
        sv += __shfl_xor(sv, 4, 64);
        sv += __shfl_xor(sv, 2, 64);
        sv += __shfl_xor(sv, 1, 64);
        if (l == 0) red[w] = __builtin_amdgcn_rcpf(sv);
    }
    __syncthreads();
    float c0 = 0.f, c1 = 0.f, c2 = 0.f, c3 = 0.f;
    for (int n = 0; n < N; ++n) {
        float e = b2f(*(const bf16*)&hEnc[n * 264 + tid]);
        c0 += a[0][n] * e;
        c1 += a[1][n] * e;
        c2 += a[2][n] * e;
        c3 += a[3][n] * e;
    }
    cx[0 * H + tid] = c0 * red[0];
    cx[1 * H + tid] = c1 * red[1];
    cx[2 * H + tid] = c2 * red[2];
    cx[3 * H + tid] = c3 * red[3];
    __syncthreads();
    const bf16* wm = (const bf16*)wmh;
    float acc = 0.f;
    for (int j = 0; j < M * H; ++j) acc += cx[j] * b2f(wm[(size_t)j * H + tid]);
    qy[tid] = acc;
    __syncthreads();
    const bf16* w2 = (const bf16*)wq2;
    float acc2 = 0.f;
    for (int k = 0; k < H; ++k) acc2 += qy[k] * b2f(w2[(size_t)k * H + tid]);
    q2[(size_t)b * H + tid] = acc2;
}

// ---------------- clip + mask + log_softmax (wave-parallel) ----------------
__global__ __launch_bounds__(128) void final_out_k(const float* __restrict__ u2,
                                                   const int* __restrict__ mask,
                                                   float* __restrict__ out) {
    int b = blockIdx.x;
    int tid = threadIdx.x;
    __shared__ float a[128];
    __shared__ float red[2];
    float u = NEG;
    if (tid < N) {
        u = 10.f * fast_tanh(u2[(size_t)b * N + tid]);
        if (mask[(size_t)b * N + tid] > 0) u = NEG;
    }
    a[tid] = u;
    __syncthreads();
    if (tid < 64) {
        float v = fmaxf(a[tid], a[tid + 64]);
        v = fmaxf(v, __shfl_xor(v, 32, 64));
        v = fmaxf(v, __shfl_xor(v, 16, 64));
        v = fmaxf(v, __shfl_xor(v, 8, 64));
        v = fmaxf(v, __shfl_xor(v, 4, 64));
        v = fmaxf(v, __shfl_xor(v, 2, 64));
        v = fmaxf(v, __shfl_xor(v, 1, 64));
        if (tid == 0) red[0] = v;
    }
    __syncthreads();
    float mx = red[0];
    float ev = (tid < N) ? __expf(u - mx) : 0.f;
    a[tid] = ev;
    __syncthreads();
    if (tid < 64) {
        float v = a[tid] + a[tid + 64];
        v += __shfl_xor(v, 32, 64);
        v += __shfl_xor(v, 16, 64);
        v += __shfl_xor(v, 8, 64);
        v += __shfl_xor(v, 4, 64);
        v += __shfl_xor(v, 2, 64);
        v += __shfl_xor(v, 1, 64);
        if (tid == 0) red[1] = logf(v);
    }
    __syncthreads();
    if (tid < N) out[(size_t)b * N + tid] = (u - mx) - red[1];
}

extern "C" void kernel_launch(void* const* d_in, const int* in_sizes, int n_in,
                              void* d_out, int out_size, void* d_ws, size_t ws_size,
                              hipStream_t stream) {
    const float* nf     = (const float*)d_in[0];
    const float* adj    = (const float*)d_in[1];
    const int*   mask   = (const int*)d_in[2];
    const float* W_emb  = (const float*)d_in[3];
    const float* W_rel  = (const float*)d_in[4];
    const float* W_self = (const float*)d_in[5];
    const float* Vec    = (const float*)d_in[6];
    const float* W_q    = (const float*)d_in[7];
    const float* W_ref  = (const float*)d_in[8];
    const float* W_mh   = (const float*)d_in[9];
    const float* Vec2   = (const float*)d_in[10];
    const float* W_q2   = (const float*)d_in[11];
    const float* W_ref2 = (const float*)d_in[12];
    const float* dec    = (const float*)d_in[13];
    const float* v_1    = (const float*)d_in[14];
    float* out = (float*)d_out;

    char* p = (char*)d_ws;
    size_t off = 0;
    auto alloc = [&](size_t bytes) -> char* {
        char* q = p + off;
        off += (bytes + 255) & ~(size_t)255;
        return q;
    };
    bf16* hA      = (bf16*)alloc((size_t)RT * H * sizeof(bf16));
    short* adjp   = (short*)alloc((size_t)B * E * 112 * 128 * sizeof(short));
    short* wfrag  = (short*)alloc(524288 * sizeof(short));
    short* wrefT  = (short*)alloc(262144 * sizeof(short));
    short* wref2T = (short*)alloc(65536 * sizeof(short));
    short* wmh_bf = (short*)alloc(262144 * sizeof(short));
    short* wq2_bf = (short*)alloc(65536 * sizeof(short));
    short* wq_bf  = (short*)alloc(262144 * sizeof(short));
    short* wembf  = (short*)alloc(8192 * sizeof(short));
    float* enc_mean = (float*)alloc((size_t)B * H * sizeof(float));
    float* qconst   = (float*)alloc((size_t)M * H * sizeof(float));
    float* vsumb    = (float*)alloc((size_t)M * H * sizeof(float));
    float* qbuf     = (float*)alloc((size_t)B * M * H * sizeof(float));
    float* scoresb  = (float*)alloc((size_t)B * M * N * sizeof(float));
    float* q2b      = (float*)alloc((size_t)B * H * sizeof(float));
    float* u2b      = (float*)alloc((size_t)B * N * sizeof(float));

    wt_prep<<<5188, 256, 0, stream>>>(W_rel, W_self, W_ref, W_ref2, W_mh, W_q2,
                                      W_q, Vec, W_emb, dec, v_1, adj,
                                      wfrag, wrefT, wref2T, wmh_bf, wq2_bf, wq_bf, wembf,
                                      adjp, qconst, vsumb);

    enc_fused<<<B, 512, 0, stream>>>(nf, wembf, adjp, wfrag, hA, enc_mean);

    const bf16* enc = hA;

    q_k<<<B * M, 256, 0, stream>>>(enc_mean, wq_bf, qconst, qbuf);
    head2_mfma<<<RT / 128, 256, 0, stream>>>(enc, wrefT, qbuf, M * H, vsumb, scoresb, M * N, M);
    dec_mid_k<<<B, 256, 0, stream>>>(scoresb, mask, enc, wmh_bf, wq2_bf, q2b);
    head2_mfma<<<RT / 128, 256, 0, stream>>>(enc, wref2T, q2b, H, Vec2, u2b, N, 1);
    final_out_k<<<B, 128, 0, stream>>>(u2b, mask, out);
}